// Round 1
// baseline (243.241 us; speedup 1.0000x reference)
//
#include <hip/hip_runtime.h>
#include <hip/hip_bf16.h>

// SpaAggregator: out[b, :] = (1/K) * sum_k table[idx[b, k], :]
//   table: [V, D] fp32 (V=200000, D=128 -> 102.4 MB, fits in 256 MiB L3)
//   idx:   [B, K] int   (B=50000, K=32)
//   out:   [B, D] fp32
//
// One wave (64 lanes) per node:
//   chunk = lane & 31  -> which float4 of the 128-float row (32 chunks)
//   sub   = lane >> 5  -> which half of the K neighbors this lane sums
// Each lane issues K/2 independent global_load_dwordx4 (random rows ->
// latency-bound; independence gives the memory pipe 16 outstanding loads).
// Index row is loaded once per wave (one idx per lane) and broadcast with
// __shfl; halves are combined with __shfl_xor(32); lanes 0..31 store float4.

#define FEAT_D 128            // floats per row
#define CHUNKS (FEAT_D / 4)   // 32 float4 chunks per row

__global__ __launch_bounds__(256) void spa_gather_mean(
    const float* __restrict__ table,
    const int* __restrict__ idx,
    float* __restrict__ out,
    int B, int K, float invK)
{
    const int wave = threadIdx.x >> 6;               // 0..3
    const int lane = threadIdx.x & 63;
    const int node = blockIdx.x * 4 + wave;
    if (node >= B) return;

    const int chunk = lane & 31;                     // float4 index in row
    const int sub   = lane >> 5;                     // 0 or 1

    // One index per lane (lanes 0..31 hold idx[node*K + 0..31]; K <= 32 here).
    int my_idx = 0;
    if (chunk < K) my_idx = idx[(long)node * K + chunk];

    const float4* __restrict__ tbl4 = (const float4*)table;

    float4 acc = make_float4(0.f, 0.f, 0.f, 0.f);

    // K == 32 fast path: fully unrolled, 16 independent loads per lane.
    if (K == 32) {
        #pragma unroll
        for (int i = 0; i < 16; ++i) {
            const int k = 2 * i + sub;
            const int row = __shfl(my_idx, k);       // lane k holds idx[k]
            const float4 v = tbl4[(long)row * CHUNKS + chunk];
            acc.x += v.x; acc.y += v.y; acc.z += v.z; acc.w += v.w;
        }
    } else {
        for (int k = sub; k < K; k += 2) {
            const int row = __shfl(my_idx, k);
            const float4 v = tbl4[(long)row * CHUNKS + chunk];
            acc.x += v.x; acc.y += v.y; acc.z += v.z; acc.w += v.w;
        }
    }

    // Combine the two neighbor-halves (lane l <-> lane l^32).
    acc.x += __shfl_xor(acc.x, 32);
    acc.y += __shfl_xor(acc.y, 32);
    acc.z += __shfl_xor(acc.z, 32);
    acc.w += __shfl_xor(acc.w, 32);

    if (sub == 0) {
        float4 r;
        r.x = acc.x * invK;
        r.y = acc.y * invK;
        r.z = acc.z * invK;
        r.w = acc.w * invK;
        ((float4*)out)[(long)node * CHUNKS + chunk] = r;
    }
}

extern "C" void kernel_launch(void* const* d_in, const int* in_sizes, int n_in,
                              void* d_out, int out_size, void* d_ws, size_t ws_size,
                              hipStream_t stream)
{
    const float* table = (const float*)d_in[0];
    const int*   idx   = (const int*)d_in[1];
    // d_in[2] is the num_sample scalar on device; K derived host-side instead.

    float* out = (float*)d_out;

    const int B = out_size / FEAT_D;          // out is [B, 128]
    const int K = in_sizes[1] / B;            // idx is [B, K]
    const float invK = 1.0f / (float)K;

    const int nodes_per_block = 4;            // 4 waves of 64 per block
    const int grid = (B + nodes_per_block - 1) / nodes_per_block;

    spa_gather_mean<<<grid, 256, 0, stream>>>(table, idx, out, B, K, invK);
}